// Round 6
// baseline (179.181 us; speedup 1.0000x reference)
//
#include <hip/hip_runtime.h>
#include <hip/hip_bf16.h>

typedef __bf16 bf16;
typedef bf16 bf16x8 __attribute__((ext_vector_type(8)));
typedef bf16 bf16x4 __attribute__((ext_vector_type(4)));
typedef float f32x4 __attribute__((ext_vector_type(4)));

#define CB 16
#define CC 256
#define CH 64
#define CW 64
#define CN 4096
#define NHEADS 8
#define NPOINTS 4
#define HDIM 32
#define SNB 8   // n's per sampling block

#define MFMA16(a, b, c) __builtin_amdgcn_mfma_f32_16x16x32_bf16(a, b, c, 0, 0, 0)

// ---------------- PE table: pe[c][n] (f32) ----------------
__global__ __launch_bounds__(256) void pe_kernel(float* __restrict__ pe) {
    int idx = blockIdx.x * 256 + threadIdx.x;
    if (idx >= CC * CN) return;
    int c = idx >> 12, n = idx & (CN - 1);
    int r = n >> 6, x = n & 63;
    int i = c >> 2, t = c & 3;
    float div = __expf(-logf(10000.0f) * (float)i / 64.0f);
    float arg = ((t < 2) ? (float)(x + 1) : (float)(r + 1)) * div;
    pe[idx] = (t & 1) ? cosf(arg) : sinf(arg);
}

// ---------------- weight packing to bf16 ----------------
__global__ __launch_bounds__(256) void pack_w(const float* __restrict__ Wv,
                                              const float* __restrict__ Woff,
                                              const float* __restrict__ Wattn,
                                              const float* __restrict__ Wout,
                                              bf16* __restrict__ Wv_bf,
                                              bf16* __restrict__ W96_bf,
                                              bf16* __restrict__ Wout_bf) {
    int i = blockIdx.x * 256 + threadIdx.x;
    if (i < CC * CC) {
        Wv_bf[i] = (bf16)Wv[i];
        Wout_bf[i] = (bf16)Wout[i];
    }
    if (i < 96 * CC) {
        W96_bf[i] = (bf16)((i < 64 * CC) ? Woff[i] : Wattn[i - 64 * CC]);
    }
}

// ---------------- fused value projection: value[b][k][n] f32 -> v_s bf16 [b][h][n][dd] -------
// Per-lane n; k-loop coalesced loads; swizzled single ds_write_b128; dbuf, 1 barrier/iter.
// Weights direct from L2. BM=256, BN=64, BK=64, 512 threads, grid (CN/64,1,CB)=1024.
__global__ __launch_bounds__(512) void vproj_f(const float* __restrict__ value,
                                               const bf16* __restrict__ Wv,
                                               const float* __restrict__ bv,
                                               bf16* __restrict__ v_s) {
    __shared__ __align__(16) char smem[17408];   // max(2 bufs * 8KB, T 64x66 f32)
    float* T = (float*)smem;
    const int TP = 66;

    int tid = threadIdx.x, lane = tid & 63, wave = tid >> 6;
    int wm = wave >> 1, wn = wave & 1, g = lane >> 4, lr = lane & 15;
    int n0 = blockIdx.x * 64, b = blockIdx.z;
    int nl = tid & 63, kg = tid >> 6;           // lane owns n0+nl; wave kg owns k-group
    const float* src = value + (size_t)b * CC * CN + n0 + nl;

    float v[8];
#pragma unroll
    for (int p = 0; p < 8; ++p) v[p] = src[(size_t)(kg * 8 + p) * CN];

    f32x4 acc[4][2] = {};
    for (int t = 0; t < 4; ++t) {
        bf16x8 o;
#pragma unroll
        for (int p = 0; p < 8; ++p) o[p] = (bf16)v[p];
        *(bf16x8*)(smem + (t & 1) * 8192 + nl * 128 + ((kg ^ (nl & 7)) * 16)) = o;
        __syncthreads();
        if (t < 3) {
#pragma unroll
            for (int p = 0; p < 8; ++p) v[p] = src[(size_t)((t + 1) * 64 + kg * 8 + p) * CN];
        }
#pragma unroll
        for (int ks = 0; ks < 2; ++ks) {
            bf16x8 af[4], bfr[2];
#pragma unroll
            for (int mf = 0; mf < 4; ++mf)
                af[mf] = *(const bf16x8*)&Wv[(size_t)(wm * 64 + mf * 16 + lr) * CC + t * 64 + ks * 32 + g * 8];
#pragma unroll
            for (int nf = 0; nf < 2; ++nf) {
                int row = wn * 32 + nf * 16 + lr;
                bfr[nf] = *(const bf16x8*)(smem + (t & 1) * 8192 + row * 128 + (((ks * 4 + g) ^ (row & 7)) * 16));
            }
#pragma unroll
            for (int mf = 0; mf < 4; ++mf)
#pragma unroll
                for (int nf = 0; nf < 2; ++nf)
                    acc[mf][nf] = MFMA16(af[mf], bfr[nf], acc[mf][nf]);
        }
    }

    // ---- epilogue: drain 64 co-rows per pass through T so v_s writes are full 64B rows ----
    int q = tid & 3, n_l = (tid >> 2) & 63, hh = tid >> 8;   // hh 0..1
#pragma unroll
    for (int pass = 0; pass < 4; ++pass) {
        __syncthreads();
        if (wm == pass) {
#pragma unroll
            for (int mf = 0; mf < 4; ++mf)
#pragma unroll
                for (int nf = 0; nf < 2; ++nf)
#pragma unroll
                    for (int i = 0; i < 4; ++i)
                        T[(mf * 16 + g * 4 + i) * TP + wn * 32 + nf * 16 + lr] = acc[mf][nf][i];
        }
        __syncthreads();
        int head = pass * 2 + hh;
        bf16x8 o;
#pragma unroll
        for (int u = 0; u < 8; ++u)
            o[u] = (bf16)(T[(hh * 32 + q * 8 + u) * TP + n_l] + bv[pass * 64 + hh * 32 + q * 8 + u]);
        *(bf16x8*)&v_s[(((size_t)b * NHEADS + head) * CN + n0 + n_l) * HDIM + q * 8] = o;
    }
}

// ---------------- fused off+attn: (query+pe)[b][k][n] -> oa f32 [b][96][n] -----------------
// M=96, BN=64, BK=64, 256 threads, grid (CN/64,1,CB)=1024.
__global__ __launch_bounds__(256) void offattn_f(const float* __restrict__ query,
                                                 const float* __restrict__ pe,
                                                 const bf16* __restrict__ W96,
                                                 const float* __restrict__ boff,
                                                 const float* __restrict__ battn,
                                                 float* __restrict__ oa) {
    __shared__ __align__(16) char smem[16384];   // 2 bufs * 8KB
    int tid = threadIdx.x, lane = tid & 63, wave = tid >> 6;
    int wm = wave >> 1, wn = wave & 1, g = lane >> 4, lr = lane & 15;
    int n0 = blockIdx.x * 64, b = blockIdx.z;
    int nl = tid & 63, kg = tid >> 6;            // kg 0..3, 16 k's each
    const float* qs = query + (size_t)b * CC * CN + n0 + nl;
    const float* ps = pe + n0 + nl;

    float v[16];
#pragma unroll
    for (int p = 0; p < 16; ++p) {
        size_t off = (size_t)(kg * 16 + p) * CN;
        v[p] = qs[off] + ps[off];
    }

    f32x4 acc[3][2] = {};
    for (int t = 0; t < 4; ++t) {
#pragma unroll
        for (int half = 0; half < 2; ++half) {
            bf16x8 o;
#pragma unroll
            for (int p = 0; p < 8; ++p) o[p] = (bf16)v[half * 8 + p];
            int slot = (kg * 2 + half) ^ (nl & 7);
            *(bf16x8*)(smem + (t & 1) * 8192 + nl * 128 + slot * 16) = o;
        }
        __syncthreads();
        if (t < 3) {
#pragma unroll
            for (int p = 0; p < 16; ++p) {
                size_t off = (size_t)((t + 1) * 64 + kg * 16 + p) * CN;
                v[p] = qs[off] + ps[off];
            }
        }
#pragma unroll
        for (int ks = 0; ks < 2; ++ks) {
            bf16x8 af[3], bfr[2];
#pragma unroll
            for (int mf = 0; mf < 3; ++mf)
                af[mf] = *(const bf16x8*)&W96[(size_t)(wm * 48 + mf * 16 + lr) * CC + t * 64 + ks * 32 + g * 8];
#pragma unroll
            for (int nf = 0; nf < 2; ++nf) {
                int row = wn * 32 + nf * 16 + lr;
                bfr[nf] = *(const bf16x8*)(smem + (t & 1) * 8192 + row * 128 + (((ks * 4 + g) ^ (row & 7)) * 16));
            }
#pragma unroll
            for (int mf = 0; mf < 3; ++mf)
#pragma unroll
                for (int nf = 0; nf < 2; ++nf)
                    acc[mf][nf] = MFMA16(af[mf], bfr[nf], acc[mf][nf]);
        }
    }
    // ---- epilogue: oa[b][96][n] — 64B runs along n ----
#pragma unroll
    for (int mf = 0; mf < 3; ++mf) {
#pragma unroll
        for (int i = 0; i < 4; ++i) {
            int j = wm * 48 + mf * 16 + g * 4 + i;
            float bias = (j < 64) ? boff[j] : battn[j - 64];
#pragma unroll
            for (int nf = 0; nf < 2; ++nf) {
                int n = wn * 32 + nf * 16 + lr;
                oa[((size_t)b * 96 + j) * CN + n0 + n] = acc[mf][nf][i] + bias;
            }
        }
    }
}

// ---------------- sampling: two-phase -> s bf16 [b][n][256]; oa is [b][96][n] --------------
__global__ __launch_bounds__(256) void sample_kernel(const float* __restrict__ oa,
                                                     const bf16* __restrict__ v_s,
                                                     bf16* __restrict__ s) {
    __shared__ int   lidx[SNB][NHEADS][NPOINTS][4];
    __shared__ float lwgt[SNB][NHEADS][NPOINTS][4];
    int bn0 = blockIdx.x * SNB;
    int b = bn0 >> 12;
    int tid = threadIdx.x;
    const float* ob = oa + (size_t)b * 96 * CN;

    {
        int nl = tid >> 5, head = (tid >> 2) & 7, p = tid & 3;
        int bn = bn0 + nl;
        int n = bn & (CN - 1);
        float lg0 = ob[(size_t)(64 + head * 4 + 0) * CN + n];
        float lg1 = ob[(size_t)(64 + head * 4 + 1) * CN + n];
        float lg2 = ob[(size_t)(64 + head * 4 + 2) * CN + n];
        float lg3 = ob[(size_t)(64 + head * 4 + 3) * CN + n];
        float m = fmaxf(fmaxf(lg0, lg1), fmaxf(lg2, lg3));
        float e0 = __expf(lg0 - m), e1 = __expf(lg1 - m);
        float e2 = __expf(lg2 - m), e3 = __expf(lg3 - m);
        float ep = (p == 0) ? e0 : (p == 1) ? e1 : (p == 2) ? e2 : e3;
        float a = ep / (e0 + e1 + e2 + e3);

        float off0 = ob[(size_t)(head * 8 + p * 2 + 0) * CN + n];
        float off1 = ob[(size_t)(head * 8 + p * 2 + 1) * CN + n];
        float ix = (float)(n & 63) * (64.0f / 63.0f) + off0 - 0.5f;
        float iy = (float)(n >> 6) * (64.0f / 63.0f) + off1 - 0.5f;
        float x0f = floorf(ix), y0f = floorf(iy);
        float wx = ix - x0f, wy = iy - y0f;
        int x0 = (int)x0f, y0 = (int)y0f;
        int x1 = x0 + 1, y1 = y0 + 1;
        float vx0 = (x0 >= 0 && x0 < CW) ? 1.f : 0.f;
        float vx1 = (x1 >= 0 && x1 < CW) ? 1.f : 0.f;
        float vy0 = (y0 >= 0 && y0 < CH) ? 1.f : 0.f;
        float vy1 = (y1 >= 0 && y1 < CH) ? 1.f : 0.f;
        int x0c = min(max(x0, 0), CW - 1), x1c = min(max(x1, 0), CW - 1);
        int y0c = min(max(y0, 0), CH - 1), y1c = min(max(y1, 0), CH - 1);
        lwgt[nl][head][p][0] = a * (1.f - wx) * (1.f - wy) * vx0 * vy0;
        lwgt[nl][head][p][1] = a * wx * (1.f - wy) * vx1 * vy0;
        lwgt[nl][head][p][2] = a * (1.f - wx) * wy * vx0 * vy1;
        lwgt[nl][head][p][3] = a * wx * wy * vx1 * vy1;
        lidx[nl][head][p][0] = (y0c * CW + x0c) * HDIM;
        lidx[nl][head][p][1] = (y0c * CW + x1c) * HDIM;
        lidx[nl][head][p][2] = (y1c * CW + x0c) * HDIM;
        lidx[nl][head][p][3] = (y1c * CW + x1c) * HDIM;
    }
    __syncthreads();

    int nl = tid >> 5, head = (tid >> 2) & 7, q = tid & 3;
    int bn = bn0 + nl;
    const bf16* vb = v_s + (((size_t)b * NHEADS + head) * CN) * HDIM + q * 8;
    float acc0 = 0.f, acc1 = 0.f, acc2 = 0.f, acc3 = 0.f;
    float acc4 = 0.f, acc5 = 0.f, acc6 = 0.f, acc7 = 0.f;
#pragma unroll
    for (int p = 0; p < NPOINTS; ++p) {
#pragma unroll
        for (int c = 0; c < 4; ++c) {
            float w = lwgt[nl][head][p][c];
            int id = lidx[nl][head][p][c];
            bf16x8 v = *(const bf16x8*)&vb[id];
            acc0 += w * (float)v[0];
            acc1 += w * (float)v[1];
            acc2 += w * (float)v[2];
            acc3 += w * (float)v[3];
            acc4 += w * (float)v[4];
            acc5 += w * (float)v[5];
            acc6 += w * (float)v[6];
            acc7 += w * (float)v[7];
        }
    }
    bf16x8 o;
    o[0] = (bf16)acc0; o[1] = (bf16)acc1; o[2] = (bf16)acc2; o[3] = (bf16)acc3;
    o[4] = (bf16)acc4; o[5] = (bf16)acc5; o[6] = (bf16)acc6; o[7] = (bf16)acc7;
    *(bf16x8*)&s[(size_t)bn * CC + head * HDIM + q * 8] = o;
}

// ---------------- output proj: s[b][n][256] x Wout[256][256] + residual -> out[b][c][n] -----
// A (s_t rows) staged dbuf 1-barrier; Wout direct from L2; coalesced epilogue via LDS T.
__global__ __launch_bounds__(256) void outproj_mfma(const bf16* __restrict__ s_t,
                                                    const bf16* __restrict__ Wout,
                                                    const float* __restrict__ bout,
                                                    const float* __restrict__ query,
                                                    const float* __restrict__ pe,
                                                    float* __restrict__ out) {
    __shared__ __align__(16) char smem[36864];   // 2 bufs * 128 rows * 144B; T overlays
    float* T = (float*)smem;
    const int TP = 132;

    int tid = threadIdx.x, lane = tid & 63, wave = tid >> 6;
    int wm = wave >> 1, wn = wave & 1, g = lane >> 4, lr = lane & 15;
    int n0 = blockIdx.x * 128, c0 = blockIdx.y * 128, b = blockIdx.z;
    const bf16* sb = s_t + (size_t)b * CN * CC;

    uint4 st[4];
#pragma unroll
    for (int j = 0; j < 4; ++j) {
        int i = tid + j * 256, row = i >> 3, ch = i & 7;
        st[j] = *(const uint4*)&sb[(size_t)(n0 + row) * CC + ch * 8];
    }

    f32x4 acc[4][4] = {};
    for (int t = 0; t < 4; ++t) {
#pragma unroll
        for (int j = 0; j < 4; ++j) {
            int i = tid + j * 256, row = i >> 3, ch = i & 7;
            *(uint4*)(smem + (t & 1) * 18432 + row * 144 + ch * 16) = st[j];
        }
        __syncthreads();
        if (t < 3) {
#pragma unroll
            for (int j = 0; j < 4; ++j) {
                int i = tid + j * 256, row = i >> 3, ch = i & 7;
                st[j] = *(const uint4*)&sb[(size_t)(n0 + row) * CC + (t + 1) * 64 + ch * 8];
            }
        }
#pragma unroll
        for (int ks = 0; ks < 2; ++ks) {
            bf16x8 af[4], bfr[4];
#pragma unroll
            for (int mf = 0; mf < 4; ++mf)
                af[mf] = *(const bf16x8*)(smem + (t & 1) * 18432 + (wm * 64 + mf * 16 + lr) * 144 + ks * 64 + g * 16);
#pragma unroll
            for (int nf = 0; nf < 4; ++nf)
                bfr[nf] = *(const bf16x8*)&Wout[(size_t)(c0 + wn * 64 + nf * 16 + lr) * CC + t * 64 + ks * 32 + g * 8];
#pragma unroll
            for (int mf = 0; mf < 4; ++mf)
#pragma unroll
                for (int nf = 0; nf < 4; ++nf)
                    acc[mf][nf] = MFMA16(af[mf], bfr[nf], acc[mf][nf]);
        }
        __syncthreads();
    }

    int lr5 = tid & 31, rq = tid >> 5;
#pragma unroll
    for (int ch = 0; ch < 2; ++ch) {
        if (wn == ch) {
#pragma unroll
            for (int mf = 0; mf < 4; ++mf)
#pragma unroll
                for (int nf = 0; nf < 4; ++nf) {
                    int cl = nf * 16 + lr;
                    int nl = wm * 64 + mf * 16 + g * 4;
                    *(f32x4*)&T[cl * TP + nl] = acc[mf][nf];
                }
        }
        __syncthreads();
#pragma unroll
        for (int pass = 0; pass < 8; ++pass) {
            int cl = pass * 8 + rq;
            int c = c0 + ch * 64 + cl;
            int n = n0 + lr5 * 4;
            f32x4 v = *(const f32x4*)&T[cl * TP + lr5 * 4];
            size_t base = ((size_t)b * CC + c) * CN + n;
            f32x4 q4 = *(const f32x4*)&query[base];
            f32x4 p4 = *(const f32x4*)&pe[(size_t)c * CN + n];
            float bias = bout[c];
#pragma unroll
            for (int j = 0; j < 4; ++j) v[j] = v[j] + bias + 2.0f * (q4[j] + p4[j]);
            *(f32x4*)&out[base] = v;
        }
        __syncthreads();
    }
}

extern "C" void kernel_launch(void* const* d_in, const int* in_sizes, int n_in,
                              void* d_out, int out_size, void* d_ws, size_t ws_size,
                              hipStream_t stream) {
    const float* query = (const float*)d_in[0];
    const float* value = (const float*)d_in[1];
    const float* W_off = (const float*)d_in[2];
    const float* b_off = (const float*)d_in[3];
    const float* W_attn = (const float*)d_in[4];
    const float* b_attn = (const float*)d_in[5];
    const float* W_val = (const float*)d_in[6];
    const float* b_val = (const float*)d_in[7];
    const float* W_out = (const float*)d_in[8];
    const float* b_out = (const float*)d_in[9];
    float* out = (float*)d_out;

    char* p = (char*)d_ws;
    float* pe = (float*)p;            p += (size_t)CC * CN * 4;
    bf16* Wv_bf = (bf16*)p;           p += (size_t)CC * CC * 2;
    bf16* Wout_bf = (bf16*)p;         p += (size_t)CC * CC * 2;
    bf16* W96_bf = (bf16*)p;          p += (size_t)96 * CC * 2 + 256;
    bf16* v_s = (bf16*)p;             p += (size_t)CB * NHEADS * CN * HDIM * 2;
    float* oa = (float*)p;            p += (size_t)CB * 96 * CN * 4;
    bf16* s_t = (bf16*)p;             p += (size_t)CB * CN * CC * 2;

    pe_kernel<<<dim3((CC * CN + 255) / 256), dim3(256), 0, stream>>>(pe);
    pack_w<<<dim3(256), dim3(256), 0, stream>>>(W_val, W_off, W_attn, W_out,
                                                Wv_bf, W96_bf, Wout_bf);
    vproj_f<<<dim3(CN / 64, 1, CB), dim3(512), 0, stream>>>(value, Wv_bf, b_val, v_s);
    offattn_f<<<dim3(CN / 64, 1, CB), dim3(256), 0, stream>>>(query, pe, W96_bf,
                                                              b_off, b_attn, oa);
    sample_kernel<<<dim3(CB * CN / SNB), dim3(256), 0, stream>>>(oa, v_s, s_t);
    outproj_mfma<<<dim3(CN / 128, CC / 128, CB), dim3(256), 0, stream>>>(s_t, Wout_bf, b_out,
                                                                         query, pe, out);
}

// Round 7
// 159.417 us; speedup vs baseline: 1.1240x; 1.1240x over previous
//
#include <hip/hip_runtime.h>
#include <hip/hip_bf16.h>

typedef __bf16 bf16;
typedef bf16 bf16x8 __attribute__((ext_vector_type(8)));
typedef bf16 bf16x4 __attribute__((ext_vector_type(4)));
typedef float f32x4 __attribute__((ext_vector_type(4)));

#define CB 16
#define CC 256
#define CH 64
#define CW 64
#define CN 4096
#define NHEADS 8
#define NPOINTS 4
#define HDIM 32
#define TBP 129   // table pitch (u32) -> lane-stride 1 bank, 2-way max

#define MFMA16(a, b, c) __builtin_amdgcn_mfma_f32_16x16x32_bf16(a, b, c, 0, 0, 0)

// ---------------- PE table: pe[c][n] (f32) ----------------
__global__ __launch_bounds__(256) void pe_kernel(float* __restrict__ pe) {
    int idx = blockIdx.x * 256 + threadIdx.x;
    if (idx >= CC * CN) return;
    int c = idx >> 12, n = idx & (CN - 1);
    int r = n >> 6, x = n & 63;
    int i = c >> 2, t = c & 3;
    float div = __expf(-logf(10000.0f) * (float)i / 64.0f);
    float arg = ((t < 2) ? (float)(x + 1) : (float)(r + 1)) * div;
    pe[idx] = (t & 1) ? cosf(arg) : sinf(arg);
}

// ---------------- weight packing to bf16 ----------------
__global__ __launch_bounds__(256) void pack_w(const float* __restrict__ Wv,
                                              const float* __restrict__ Woff,
                                              const float* __restrict__ Wattn,
                                              const float* __restrict__ Wout,
                                              bf16* __restrict__ Wv_bf,
                                              bf16* __restrict__ W96_bf,
                                              bf16* __restrict__ Wout_bf) {
    int i = blockIdx.x * 256 + threadIdx.x;
    if (i < CC * CC) {
        Wv_bf[i] = (bf16)Wv[i];
        Wout_bf[i] = (bf16)Wout[i];
    }
    if (i < 96 * CC) {
        W96_bf[i] = (bf16)((i < 64 * CC) ? Woff[i] : Wattn[i - 64 * CC]);
    }
}

// ---------------- fused value projection (unchanged from r6) ----------------
__global__ __launch_bounds__(512) void vproj_f(const float* __restrict__ value,
                                               const bf16* __restrict__ Wv,
                                               const float* __restrict__ bv,
                                               bf16* __restrict__ v_s) {
    __shared__ __align__(16) char smem[17408];
    float* T = (float*)smem;
    const int TP = 66;

    int tid = threadIdx.x, lane = tid & 63, wave = tid >> 6;
    int wm = wave >> 1, wn = wave & 1, g = lane >> 4, lr = lane & 15;
    int n0 = blockIdx.x * 64, b = blockIdx.z;
    int nl = tid & 63, kg = tid >> 6;
    const float* src = value + (size_t)b * CC * CN + n0 + nl;

    float v[8];
#pragma unroll
    for (int p = 0; p < 8; ++p) v[p] = src[(size_t)(kg * 8 + p) * CN];

    f32x4 acc[4][2] = {};
    for (int t = 0; t < 4; ++t) {
        bf16x8 o;
#pragma unroll
        for (int p = 0; p < 8; ++p) o[p] = (bf16)v[p];
        *(bf16x8*)(smem + (t & 1) * 8192 + nl * 128 + ((kg ^ (nl & 7)) * 16)) = o;
        __syncthreads();
        if (t < 3) {
#pragma unroll
            for (int p = 0; p < 8; ++p) v[p] = src[(size_t)((t + 1) * 64 + kg * 8 + p) * CN];
        }
#pragma unroll
        for (int ks = 0; ks < 2; ++ks) {
            bf16x8 af[4], bfr[2];
#pragma unroll
            for (int mf = 0; mf < 4; ++mf)
                af[mf] = *(const bf16x8*)&Wv[(size_t)(wm * 64 + mf * 16 + lr) * CC + t * 64 + ks * 32 + g * 8];
#pragma unroll
            for (int nf = 0; nf < 2; ++nf) {
                int row = wn * 32 + nf * 16 + lr;
                bfr[nf] = *(const bf16x8*)(smem + (t & 1) * 8192 + row * 128 + (((ks * 4 + g) ^ (row & 7)) * 16));
            }
#pragma unroll
            for (int mf = 0; mf < 4; ++mf)
#pragma unroll
                for (int nf = 0; nf < 2; ++nf)
                    acc[mf][nf] = MFMA16(af[mf], bfr[nf], acc[mf][nf]);
        }
    }

    int q = tid & 3, n_l = (tid >> 2) & 63, hh = tid >> 8;
#pragma unroll
    for (int pass = 0; pass < 4; ++pass) {
        __syncthreads();
        if (wm == pass) {
#pragma unroll
            for (int mf = 0; mf < 4; ++mf)
#pragma unroll
                for (int nf = 0; nf < 2; ++nf)
#pragma unroll
                    for (int i = 0; i < 4; ++i)
                        T[(mf * 16 + g * 4 + i) * TP + wn * 32 + nf * 16 + lr] = acc[mf][nf][i];
        }
        __syncthreads();
        int head = pass * 2 + hh;
        bf16x8 o;
#pragma unroll
        for (int u = 0; u < 8; ++u)
            o[u] = (bf16)(T[(hh * 32 + q * 8 + u) * TP + n_l] + bv[pass * 64 + hh * 32 + q * 8 + u]);
        *(bf16x8*)&v_s[(((size_t)b * NHEADS + head) * CN + n0 + n_l) * HDIM + q * 8] = o;
    }
}

// ---------------- fused off+attn+sampling: -> s bf16 [b][n][256] (no oa tensor) -------------
// GEMM (96 x 64n) -> LDS ot[96][65] -> phase1 packed (f16 w | cell) tables -> phase2 gathers.
__global__ __launch_bounds__(256) void offattn_sample(const float* __restrict__ query,
                                                      const float* __restrict__ pe,
                                                      const bf16* __restrict__ W96,
                                                      const float* __restrict__ boff,
                                                      const float* __restrict__ battn,
                                                      const bf16* __restrict__ v_s,
                                                      bf16* __restrict__ s) {
    __shared__ __align__(16) char smem[33024];   // stage 16KB / ot 25KB / tbl 33KB (overlaid)
    float* ot = (float*)smem;                    // [96][65]
    unsigned* tbl = (unsigned*)smem;             // [64][TBP] (h*16+e within row)

    int tid = threadIdx.x, lane = tid & 63, wave = tid >> 6;
    int wm = wave >> 1, wn = wave & 1, g = lane >> 4, lr = lane & 15;
    int bx = blockIdx.x, b = blockIdx.z;
    int n0 = bx * 64;
    int nl = tid & 63, kg = tid >> 6;
    const float* qs = query + (size_t)b * CC * CN + n0 + nl;
    const float* ps = pe + n0 + nl;

    float v[16];
#pragma unroll
    for (int p = 0; p < 16; ++p) {
        size_t off = (size_t)(kg * 16 + p) * CN;
        v[p] = qs[off] + ps[off];
    }

    f32x4 acc[3][2] = {};
    for (int t = 0; t < 4; ++t) {
#pragma unroll
        for (int half = 0; half < 2; ++half) {
            bf16x8 o;
#pragma unroll
            for (int p = 0; p < 8; ++p) o[p] = (bf16)v[half * 8 + p];
            int slot = (kg * 2 + half) ^ (nl & 7);
            *(bf16x8*)(smem + (t & 1) * 8192 + nl * 128 + slot * 16) = o;
        }
        __syncthreads();
        if (t < 3) {
#pragma unroll
            for (int p = 0; p < 16; ++p) {
                size_t off = (size_t)((t + 1) * 64 + kg * 16 + p) * CN;
                v[p] = qs[off] + ps[off];
            }
        }
#pragma unroll
        for (int ks = 0; ks < 2; ++ks) {
            bf16x8 af[3], bfr[2];
#pragma unroll
            for (int mf = 0; mf < 3; ++mf)
                af[mf] = *(const bf16x8*)&W96[(size_t)(wm * 48 + mf * 16 + lr) * CC + t * 64 + ks * 32 + g * 8];
#pragma unroll
            for (int nf = 0; nf < 2; ++nf) {
                int row = wn * 32 + nf * 16 + lr;
                bfr[nf] = *(const bf16x8*)(smem + (t & 1) * 8192 + row * 128 + (((ks * 4 + g) ^ (row & 7)) * 16));
            }
#pragma unroll
            for (int mf = 0; mf < 3; ++mf)
#pragma unroll
                for (int nf = 0; nf < 2; ++nf)
                    acc[mf][nf] = MFMA16(af[mf], bfr[nf], acc[mf][nf]);
        }
    }
    __syncthreads();   // all MFMA reads done before ot overlays staging

    // ---- acc (+bias) -> ot[96][65] ----
#pragma unroll
    for (int mf = 0; mf < 3; ++mf) {
#pragma unroll
        for (int i = 0; i < 4; ++i) {
            int j = wm * 48 + mf * 16 + g * 4 + i;
            float bias = (j < 64) ? boff[j] : battn[j - 64];
#pragma unroll
            for (int nf = 0; nf < 2; ++nf) {
                int col = wn * 32 + nf * 16 + lr;
                ot[j * 65 + col] = acc[mf][nf][i] + bias;
            }
        }
    }
    __syncthreads();

    // ---- phase 1: per (nl,h) -> 16 packed (f16 weight | cell) in regs ----
    unsigned pk[2][16];
#pragma unroll
    for (int it = 0; it < 2; ++it) {
        int item = it * 256 + tid;
        int inl = item & 63, h = item >> 6;
        float lg0 = ot[(64 + h * 4 + 0) * 65 + inl];
        float lg1 = ot[(64 + h * 4 + 1) * 65 + inl];
        float lg2 = ot[(64 + h * 4 + 2) * 65 + inl];
        float lg3 = ot[(64 + h * 4 + 3) * 65 + inl];
        float m = fmaxf(fmaxf(lg0, lg1), fmaxf(lg2, lg3));
        float e0 = __expf(lg0 - m), e1 = __expf(lg1 - m);
        float e2 = __expf(lg2 - m), e3 = __expf(lg3 - m);
        float inv = 1.0f / (e0 + e1 + e2 + e3);
        float ep[4] = {e0, e1, e2, e3};
#pragma unroll
        for (int p = 0; p < NPOINTS; ++p) {
            float off0 = ot[(h * 8 + p * 2 + 0) * 65 + inl];
            float off1 = ot[(h * 8 + p * 2 + 1) * 65 + inl];
            float ix = (float)inl * (64.0f / 63.0f) + off0 - 0.5f;
            float iy = (float)bx * (64.0f / 63.0f) + off1 - 0.5f;
            float x0f = floorf(ix), y0f = floorf(iy);
            float wx = ix - x0f, wy = iy - y0f;
            int x0 = (int)x0f, y0 = (int)y0f;
            int x1 = x0 + 1, y1 = y0 + 1;
            float vx0 = (x0 >= 0 && x0 < CW) ? 1.f : 0.f;
            float vx1 = (x1 >= 0 && x1 < CW) ? 1.f : 0.f;
            float vy0 = (y0 >= 0 && y0 < CH) ? 1.f : 0.f;
            float vy1 = (y1 >= 0 && y1 < CH) ? 1.f : 0.f;
            int x0c = min(max(x0, 0), CW - 1), x1c = min(max(x1, 0), CW - 1);
            int y0c = min(max(y0, 0), CH - 1), y1c = min(max(y1, 0), CH - 1);
            float a = ep[p] * inv;
            float w00 = a * (1.f - wx) * (1.f - wy) * vx0 * vy0;
            float w01 = a * wx * (1.f - wy) * vx1 * vy0;
            float w10 = a * (1.f - wx) * wy * vx0 * vy1;
            float w11 = a * wx * wy * vx1 * vy1;
            unsigned c00 = (unsigned)(y0c * CW + x0c), c01 = (unsigned)(y0c * CW + x1c);
            unsigned c10 = (unsigned)(y1c * CW + x0c), c11 = (unsigned)(y1c * CW + x1c);
            pk[it][p * 4 + 0] = ((unsigned)__builtin_bit_cast(unsigned short, (_Float16)w00) << 16) | c00;
            pk[it][p * 4 + 1] = ((unsigned)__builtin_bit_cast(unsigned short, (_Float16)w01) << 16) | c01;
            pk[it][p * 4 + 2] = ((unsigned)__builtin_bit_cast(unsigned short, (_Float16)w10) << 16) | c10;
            pk[it][p * 4 + 3] = ((unsigned)__builtin_bit_cast(unsigned short, (_Float16)w11) << 16) | c11;
        }
    }
    __syncthreads();   // ot reads done before tbl overlays it
#pragma unroll
    for (int it = 0; it < 2; ++it) {
        int item = it * 256 + tid;
        int inl = item & 63, h = item >> 6;
        unsigned* dst = tbl + inl * TBP + h * 16;
#pragma unroll
        for (int e = 0; e < 16; ++e) dst[e] = pk[it][e];
    }
    __syncthreads();

    // ---- phase 2: (nl, h, q) wide gathers -> s ----
    int q = tid & 3, h2 = (tid >> 2) & 7, ng = tid >> 5;
    const bf16* vb = v_s + (((size_t)b * NHEADS + h2) * CN) * HDIM + q * 8;
#pragma unroll
    for (int iter = 0; iter < 8; ++iter) {
        int snl = iter * 8 + ng;
        const unsigned* tb = tbl + snl * TBP + h2 * 16;
        float a0 = 0.f, a1 = 0.f, a2 = 0.f, a3 = 0.f;
        float a4 = 0.f, a5 = 0.f, a6 = 0.f, a7 = 0.f;
#pragma unroll
        for (int e = 0; e < 16; ++e) {
            unsigned u = tb[e];
            float w = (float)__builtin_bit_cast(_Float16, (unsigned short)(u >> 16));
            int cell = (int)(u & 0xFFFu);
            bf16x8 gv = *(const bf16x8*)&vb[cell * HDIM];
            a0 += w * (float)gv[0]; a1 += w * (float)gv[1];
            a2 += w * (float)gv[2]; a3 += w * (float)gv[3];
            a4 += w * (float)gv[4]; a5 += w * (float)gv[5];
            a6 += w * (float)gv[6]; a7 += w * (float)gv[7];
        }
        bf16x8 o;
        o[0] = (bf16)a0; o[1] = (bf16)a1; o[2] = (bf16)a2; o[3] = (bf16)a3;
        o[4] = (bf16)a4; o[5] = (bf16)a5; o[6] = (bf16)a6; o[7] = (bf16)a7;
        *(bf16x8*)&s[((size_t)b * CN + n0 + snl) * CC + h2 * 32 + q * 8] = o;
    }
}

// ---------------- output proj v3: swizzled LDS both operands, XCD-chunked grid --------------
__global__ __launch_bounds__(256) void outproj_v3(const bf16* __restrict__ s_t,
                                                  const bf16* __restrict__ Wout,
                                                  const float* __restrict__ bout,
                                                  const float* __restrict__ query,
                                                  const float* __restrict__ pe,
                                                  float* __restrict__ out) {
    __shared__ __align__(16) char smem[33792];   // As 16KB | Bs 16KB ; T[64][132] overlays
    float* T = (float*)smem;
    const int TP = 132;

    int tid = threadIdx.x, lane = tid & 63, wave = tid >> 6;
    int wm = wave >> 1, wn = wave & 1, g = lane >> 4, lr = lane & 15;
    int id = blockIdx.x;
    int swz = (id & 7) * 128 + (id >> 3);        // 8 XCDs x 128-block chunks (2 batches each)
    int n0 = (swz & 31) * 128, c0 = ((swz >> 5) & 1) * 128, b = swz >> 6;
    const bf16* sb = s_t + ((size_t)b * CN + n0) * CC;

    f32x4 acc[4][4] = {};
    for (int t = 0; t < 4; ++t) {
        if (t) __syncthreads();
        uint4 ra[4], rw[4];
#pragma unroll
        for (int j = 0; j < 4; ++j) {
            int idx = tid + j * 256, row = idx >> 3, ch = idx & 7;
            ra[j] = *(const uint4*)&sb[(size_t)row * CC + t * 64 + ch * 8];
            rw[j] = *(const uint4*)&Wout[(size_t)(c0 + row) * CC + t * 64 + ch * 8];
        }
#pragma unroll
        for (int j = 0; j < 4; ++j) {
            int idx = tid + j * 256, row = idx >> 3, ch = idx & 7;
            int so = row * 128 + ((ch ^ (row & 7)) * 16);
            *(uint4*)(smem + so) = ra[j];
            *(uint4*)(smem + 16384 + so) = rw[j];
        }
        __syncthreads();
#pragma unroll
        for (int ks = 0; ks < 2; ++ks) {
            bf16x8 af[4], bfr[4];
#pragma unroll
            for (int mf = 0; mf < 4; ++mf) {
                int row = wm * 64 + mf * 16 + lr;
                af[mf] = *(const bf16x8*)(smem + row * 128 + (((ks * 4 + g) ^ (row & 7)) * 16));
            }
#pragma unroll
            for (int nf = 0; nf < 4; ++nf) {
                int row = wn * 64 + nf * 16 + lr;
                bfr[nf] = *(const bf16x8*)(smem + 16384 + row * 128 + (((ks * 4 + g) ^ (row & 7)) * 16));
            }
#pragma unroll
            for (int mf = 0; mf < 4; ++mf)
#pragma unroll
                for (int nf = 0; nf < 4; ++nf)
                    acc[mf][nf] = MFMA16(af[mf], bfr[nf], acc[mf][nf]);
        }
    }
    __syncthreads();

    int lr5 = tid & 31, rq = tid >> 5;
#pragma unroll
    for (int ch = 0; ch < 2; ++ch) {
        if (wn == ch) {
#pragma unroll
            for (int mf = 0; mf < 4; ++mf)
#pragma unroll
                for (int nf = 0; nf < 4; ++nf) {
                    int cl = nf * 16 + lr;
                    int nl = wm * 64 + mf * 16 + g * 4;
                    *(f32x4*)&T[cl * TP + nl] = acc[mf][nf];
                }
        }
        __syncthreads();
#pragma unroll
        for (int pass = 0; pass < 8; ++pass) {
            int cl = pass * 8 + rq;
            int c = c0 + ch * 64 + cl;
            int n = n0 + lr5 * 4;
            f32x4 v = *(const f32x4*)&T[cl * TP + lr5 * 4];
            size_t base = ((size_t)b * CC + c) * CN + n;
            f32x4 q4 = *(const f32x4*)&query[base];
            f32x4 p4 = *(const f32x4*)&pe[(size_t)c * CN + n];
            float bias = bout[c];
#pragma unroll
            for (int j = 0; j < 4; ++j) v[j] = v[j] + bias + 2.0f * (q4[j] + p4[j]);
            *(f32x4*)&out[base] = v;
        }
        __syncthreads();
    }
}

extern "C" void kernel_launch(void* const* d_in, const int* in_sizes, int n_in,
                              void* d_out, int out_size, void* d_ws, size_t ws_size,
                              hipStream_t stream) {
    const float* query = (const float*)d_in[0];
    const float* value = (const float*)d_in[1];
    const float* W_off = (const float*)d_in[2];
    const float* b_off = (const float*)d_in[3];
    const float* W_attn = (const float*)d_in[4];
    const float* b_attn = (const float*)d_in[5];
    const float* W_val = (const float*)d_in[6];
    const float* b_val = (const float*)d_in[7];
    const float* W_out = (const float*)d_in[8];
    const float* b_out = (const float*)d_in[9];
    float* out = (float*)d_out;

    char* p = (char*)d_ws;
    float* pe = (float*)p;            p += (size_t)CC * CN * 4;
    bf16* Wv_bf = (bf16*)p;           p += (size_t)CC * CC * 2;
    bf16* Wout_bf = (bf16*)p;         p += (size_t)CC * CC * 2;
    bf16* W96_bf = (bf16*)p;          p += (size_t)96 * CC * 2 + 256;
    bf16* v_s = (bf16*)p;             p += (size_t)CB * NHEADS * CN * HDIM * 2;
    bf16* s_t = (bf16*)p;             p += (size_t)CB * CN * CC * 2;

    pe_kernel<<<dim3((CC * CN + 255) / 256), dim3(256), 0, stream>>>(pe);
    pack_w<<<dim3(256), dim3(256), 0, stream>>>(W_val, W_off, W_attn, W_out,
                                                Wv_bf, W96_bf, Wout_bf);
    vproj_f<<<dim3(CN / 64, 1, CB), dim3(512), 0, stream>>>(value, Wv_bf, b_val, v_s);
    offattn_sample<<<dim3(CN / 64, 1, CB), dim3(256), 0, stream>>>(query, pe, W96_bf,
                                                                   b_off, b_attn, v_s, s_t);
    outproj_v3<<<dim3(1024), dim3(256), 0, stream>>>(s_t, Wout_bf, b_out, query, pe, out);
}